// Round 8
// baseline (60.960 us; speedup 1.0000x reference)
//
#include <hip/hip_runtime.h>
#include <math.h>

#define NACC 24
#define GRID1 1024
#define TPB 256
// 1024 blocks x 256 threads x 16 elements = 4194304 exactly

// canonical 24-vector layout:
//  0: lt count (dbp_pred < sbp_pred)
//  1: sum_d   2: sum_d2   3: sum_dp  4: sum_dp2
//  5: sum_s   6: sum_s2   7: sum_sp  8: sum_sp2
//  9+3g: mask-g count   10+3g: mask-g . smape_d   11+3g: mask-g . smape_s

// All-f32 per-thread accumulation (16 elems/thread): sums ~1e-7 rel error,
// counts <= 16 exact in f32; promoted to f64 before cross-thread summation.
// Accumulation via w in {0,1} + fma is bit-identical to cndmask'd adds.
__device__ __forceinline__ void process_elem(float* a, float dpv, float spv,
                                             float dv, float sv) {
    a[0] += (dpv < spv) ? 1.0f : 0.0f;
    a[1] += dv;  a[2] = fmaf(dv,  dv,  a[2]);
    a[3] += dpv; a[4] = fmaf(dpv, dpv, a[4]);
    a[5] += sv;  a[6] = fmaf(sv,  sv,  a[6]);
    a[7] += spv; a[8] = fmaf(spv, spv, a[8]);
    float smd = 2.0f * fabsf(dpv - dv) * __builtin_amdgcn_rcpf(fabsf(dpv) + fabsf(dv));
    float sms = 2.0f * fabsf(spv - sv) * __builtin_amdgcn_rcpf(fabsf(spv) + fabsf(sv));
    // mask precedence: & binds tighter than | in the reference
    bool m0 = (sv < 120.0f) && (dv < 80.0f);
    bool m1 = (sv >= 120.0f) && (sv < 130.0f) && (dv < 80.0f);
    bool m2 = ((sv >= 130.0f) && (sv < 140.0f)) || ((dv >= 80.0f) && (dv < 90.0f));
    bool m3 = (sv >= 140.0f) || (dv >= 90.0f);
    bool m4 = (sv > 180.0f) || (dv > 120.0f);
    float w;
    w = m0 ? 1.0f : 0.0f; a[9]  += w; a[10] = fmaf(w, smd, a[10]); a[11] = fmaf(w, sms, a[11]);
    w = m1 ? 1.0f : 0.0f; a[12] += w; a[13] = fmaf(w, smd, a[13]); a[14] = fmaf(w, sms, a[14]);
    w = m2 ? 1.0f : 0.0f; a[15] += w; a[16] = fmaf(w, smd, a[16]); a[17] = fmaf(w, sms, a[17]);
    w = m3 ? 1.0f : 0.0f; a[18] += w; a[19] = fmaf(w, smd, a[19]); a[20] = fmaf(w, sms, a[20]);
    w = m4 ? 1.0f : 0.0f; a[21] += w; a[22] = fmaf(w, smd, a[22]); a[23] = fmaf(w, sms, a[23]);
}

__device__ __forceinline__ void process4(float* a, float4 vdp, float4 vsp,
                                         float4 vd, float4 vs) {
    process_elem(a, vdp.x, vsp.x, vd.x, vs.x);
    process_elem(a, vdp.y, vsp.y, vd.y, vs.y);
    process_elem(a, vdp.z, vsp.z, vd.z, vs.z);
    process_elem(a, vdp.w, vsp.w, vd.w, vs.w);
}

// Single fused kernel. Per block: grind 16 elems/thread -> LDS store-gather
// block reduction -> thread 0 publishes 24 f64 slots + __threadfence +
// atomicAdd ticket. The unique last block acquire-fences and reduces the
// 24 x GRID1 partial matrix in-block, then computes the scalar tail.
template <bool EXACT>
__global__ __launch_bounds__(TPB, 4) void amp_fused(
    const float* __restrict__ dp, const float* __restrict__ sp,
    const float* __restrict__ d,  const float* __restrict__ s,
    double* __restrict__ partial, unsigned int* __restrict__ counter,
    float* __restrict__ out, int n)
{
    __shared__ float    red[NACC][TPB];   // 24 KB
    __shared__ double   red2[NACC][8];
    __shared__ double   blk24[NACC];
    __shared__ unsigned lastflag;

    const int tid  = threadIdx.x;
    const int bid  = blockIdx.x;
    const int n4   = n >> 2;
    const int gtid = bid * TPB + tid;
    const int S    = GRID1 * TPB;         // float4 stride between tiles

    const float4* dp4 = (const float4*)dp;
    const float4* sp4 = (const float4*)sp;
    const float4* d4  = (const float4*)d;
    const float4* s4  = (const float4*)s;

    // stage ALL 16 independent loads into registers before any use
    float4 vdp[4], vsp[4], vd[4], vs[4];
    if (EXACT) {
        #pragma unroll
        for (int t = 0; t < 4; ++t) {
            const int i = gtid + t * S;
            vdp[t] = dp4[i]; vsp[t] = sp4[i]; vd[t] = d4[i]; vs[t] = s4[i];
        }
    } else {
        const float4 z4 = make_float4(0.f, 0.f, 0.f, 0.f);
        #pragma unroll
        for (int t = 0; t < 4; ++t) {
            const int i = gtid + t * S;
            const bool p = i < n4;
            vdp[t] = p ? dp4[i] : z4; vsp[t] = p ? sp4[i] : z4;
            vd[t]  = p ? d4[i]  : z4; vs[t]  = p ? s4[i]  : z4;
        }
    }

    float a[NACC];
    #pragma unroll
    for (int k = 0; k < NACC; ++k) a[k] = 0.0f;
    #pragma unroll
    for (int t = 0; t < 4; ++t) process4(a, vdp[t], vsp[t], vd[t], vs[t]);

    // block reduction via LDS store-then-gather (no shuffles, no atomics)
    #pragma unroll
    for (int k = 0; k < NACC; ++k) red[k][tid] = a[k];     // conflict-free
    __syncthreads();

    if (tid < 192) {
        const int k = tid >> 3;        // 0..23
        const int j = tid & 7;         // 0..7
        const float* row = &red[k][j * 32];
        double s0 = 0.0, s1 = 0.0, s2 = 0.0, s3 = 0.0;
        #pragma unroll
        for (int i = 0; i < 32; i += 4) {
            s0 += (double)row[(i + 0 + tid) & 31];
            s1 += (double)row[(i + 1 + tid) & 31];
            s2 += (double)row[(i + 2 + tid) & 31];
            s3 += (double)row[(i + 3 + tid) & 31];
        }
        red2[k][j] = (s0 + s1) + (s2 + s3);
    }
    __syncthreads();

    if (tid < NACC) {
        double v = 0.0;
        #pragma unroll
        for (int j = 0; j < 8; ++j) v += red2[tid][j];
        blk24[tid] = v;
    }
    __syncthreads();

    // single-thread release chain: store 24 slots -> fence -> ticket
    if (tid == 0) {
        #pragma unroll
        for (int k = 0; k < NACC; ++k)
            partial[k * GRID1 + bid] = blk24[k];           // transposed layout
        __threadfence();
        unsigned old = atomicAdd(counter, 1u);
        lastflag = (old == (unsigned)(GRID1 - 1)) ? 1u : 0u;
    }
    __syncthreads();
    if (!lastflag) return;

    // ---- last block: acquire + final reduction + scalar tail ----
    if (tid == 0) __threadfence();
    __syncthreads();

    __shared__ double tot[NACC];
    const int lane = tid & 63;
    const int wave = tid >> 6;
    for (int k = wave; k < NACC; k += 4) {                 // 4 waves, 6 cols each
        const double* col = partial + k * GRID1 + lane;
        double v0 = 0.0, v1 = 0.0, v2 = 0.0, v3 = 0.0;
        #pragma unroll
        for (int r = 0; r < GRID1 / 64; r += 4) {
            v0 += col[(r + 0) * 64];
            v1 += col[(r + 1) * 64];
            v2 += col[(r + 2) * 64];
            v3 += col[(r + 3) * 64];
        }
        double v = (v0 + v1) + (v2 + v3);
        #pragma unroll
        for (int off = 32; off > 0; off >>= 1)
            v += __shfl_down(v, off, 64);
        if (lane == 0) tot[k] = v;
    }
    __syncthreads();

    if (tid == 0) {
        const double nf = (double)n;
        const double lt = tot[0];
        const double sum_d  = tot[1], sum_d2  = tot[2];
        const double sum_dp = tot[3], sum_dp2 = tot[4];
        const double sum_s  = tot[5], sum_s2  = tot[6];
        const double sum_sp = tot[7], sum_sp2 = tot[8];

        double scale_cost = 1.0 - lt / nf;

        double d_rst = 0.0, s_rst = 0.0, rst_d = 0.0, rst_s = 0.0;
        int cnt = 0;
        #pragma unroll
        for (int i = 0; i < 5; ++i) {
            double c   = tot[9 + 3 * i];
            double sdi = tot[10 + 3 * i];
            double ssi = tot[11 + 3 * i];
            double safe = fmax(c, 1.0);
            double w = sqrt(log(nf / safe));
            double sum_di = w * sdi;
            double sum_si = w * ssi;
            bool has = c > 0.0;
            double nd = (d_rst + sum_di) / safe;
            double ns = (s_rst + sum_si) / safe;
            if (has) {
                d_rst = nd; s_rst = ns;
                rst_d += nd; rst_s += ns;
                cnt++;
            }
        }
        double denom = (cnt == 0) ? 5.0 : (double)cnt;
        rst_d /= denom;
        rst_s /= denom;

        double mean_d  = sum_d / nf,  mean_dp = sum_dp / nf;
        double mean_s  = sum_s / nf,  mean_sp = sum_sp / nf;
        double var_d  = (sum_d2  - nf * mean_d  * mean_d)  / (nf - 1.0);
        double var_dp = (sum_dp2 - nf * mean_dp * mean_dp) / (nf - 1.0);
        double var_s  = (sum_s2  - nf * mean_s  * mean_s)  / (nf - 1.0);
        double var_sp = (sum_sp2 - nf * mean_sp * mean_sp) / (nf - 1.0);

        double dbp_mean_cost = fabs(mean_d - mean_dp) / mean_d;
        double sbp_mean_cost = fabs(mean_s - mean_sp) / mean_s;
        double dbp_var_cost  = fabs(var_d - var_dp) / var_d;
        double sbp_var_cost  = fabs(var_s - var_sp) / var_s;

        out[0] = (float)(rst_d + dbp_mean_cost + dbp_var_cost);
        out[1] = (float)(rst_s + sbp_mean_cost + sbp_var_cost);
        out[2] = (float)scale_cost;
    }
}

extern "C" void kernel_launch(void* const* d_in, const int* in_sizes, int n_in,
                              void* d_out, int out_size, void* d_ws, size_t ws_size,
                              hipStream_t stream) {
    const float* dp = (const float*)d_in[0];   // dbp_pred
    const float* sp = (const float*)d_in[1];   // sbp_pred
    // d_in[2] = mbp_pred (unused), d_in[5] = m (unused)
    const float* d  = (const float*)d_in[3];
    const float* s  = (const float*)d_in[4];
    const int n = in_sizes[0];

    double*   partial = (double*)d_ws;                         // 192 KiB
    unsigned* counter = (unsigned*)((char*)d_ws + NACC * GRID1 * sizeof(double));
    float*    out     = (float*)d_out;

    // zero the ticket each launch (graph-capturable async memset)
    hipMemsetAsync(counter, 0, sizeof(unsigned), stream);

    if (n == GRID1 * TPB * 16) {
        hipLaunchKernelGGL((amp_fused<true>), dim3(GRID1), dim3(TPB), 0, stream,
                           dp, sp, d, s, partial, counter, out, n);
    } else {
        hipLaunchKernelGGL((amp_fused<false>), dim3(GRID1), dim3(TPB), 0, stream,
                           dp, sp, d, s, partial, counter, out, n);
    }
}

// Round 10
// 29.792 us; speedup vs baseline: 2.0462x; 2.0462x over previous
//
#include <hip/hip_runtime.h>
#include <math.h>

#define NACC 24
#define GRID1 2048
#define TPB 256
// 2048 blocks x 256 threads x 8 elements = 4194304 exactly

// canonical 24-vector layout:
//  0: lt count (dbp_pred < sbp_pred)
//  1: sum_d   2: sum_d2   3: sum_dp  4: sum_dp2
//  5: sum_s   6: sum_s2   7: sum_sp  8: sum_sp2
//  9+3g: mask-g count   10+3g: mask-g . smape_d   11+3g: mask-g . smape_s

// All-f32 per-thread accumulation (8 elems/thread): sums ~1e-7 rel error,
// counts <= 8 exact in f32; promoted to f64 before cross-thread summation.
__device__ __forceinline__ void process_elem(float* a, float dpv, float spv,
                                             float dv, float sv) {
    a[0] += (dpv < spv) ? 1.0f : 0.0f;
    a[1] += dv;  a[2] = fmaf(dv,  dv,  a[2]);
    a[3] += dpv; a[4] = fmaf(dpv, dpv, a[4]);
    a[5] += sv;  a[6] = fmaf(sv,  sv,  a[6]);
    a[7] += spv; a[8] = fmaf(spv, spv, a[8]);
    float smd = 2.0f * fabsf(dpv - dv) * __builtin_amdgcn_rcpf(fabsf(dpv) + fabsf(dv));
    float sms = 2.0f * fabsf(spv - sv) * __builtin_amdgcn_rcpf(fabsf(spv) + fabsf(sv));
    // mask precedence: & binds tighter than | in the reference
    bool m0 = (sv < 120.0f) && (dv < 80.0f);
    bool m1 = (sv >= 120.0f) && (sv < 130.0f) && (dv < 80.0f);
    bool m2 = ((sv >= 130.0f) && (sv < 140.0f)) || ((dv >= 80.0f) && (dv < 90.0f));
    bool m3 = (sv >= 140.0f) || (dv >= 90.0f);
    bool m4 = (sv > 180.0f) || (dv > 120.0f);
    float w;
    w = m0 ? 1.0f : 0.0f; a[9]  += w; a[10] = fmaf(w, smd, a[10]); a[11] = fmaf(w, sms, a[11]);
    w = m1 ? 1.0f : 0.0f; a[12] += w; a[13] = fmaf(w, smd, a[13]); a[14] = fmaf(w, sms, a[14]);
    w = m2 ? 1.0f : 0.0f; a[15] += w; a[16] = fmaf(w, smd, a[16]); a[17] = fmaf(w, sms, a[17]);
    w = m3 ? 1.0f : 0.0f; a[18] += w; a[19] = fmaf(w, smd, a[19]); a[20] = fmaf(w, sms, a[20]);
    w = m4 ? 1.0f : 0.0f; a[21] += w; a[22] = fmaf(w, smd, a[22]); a[23] = fmaf(w, sms, a[23]);
}

__device__ __forceinline__ void process4(float* a, float4 vdp, float4 vsp,
                                         float4 vd, float4 vs) {
    process_elem(a, vdp.x, vsp.x, vd.x, vs.x);
    process_elem(a, vdp.y, vsp.y, vd.y, vs.y);
    process_elem(a, vdp.z, vsp.z, vd.z, vs.z);
    process_elem(a, vdp.w, vsp.w, vd.w, vs.w);
}

template <bool EXACT>
__global__ __launch_bounds__(TPB, 4) void amp_reduce(
    const float* __restrict__ dp, const float* __restrict__ sp,
    const float* __restrict__ d,  const float* __restrict__ s,
    double* __restrict__ partial, int n)
{
    __shared__ float  red[NACC][TPB];   // 24 KB
    __shared__ double red2[NACC][8];    // 1.5 KB

    const int tid  = threadIdx.x;
    const int n4   = n >> 2;
    const int gtid = blockIdx.x * TPB + tid;
    const int S    = GRID1 * TPB;       // float4 stride between the 2 tiles

    const float4* dp4 = (const float4*)dp;
    const float4* sp4 = (const float4*)sp;
    const float4* d4  = (const float4*)d;
    const float4* s4  = (const float4*)s;

    // issue all 8 independent loads
    float4 a_dp0, a_sp0, a_d0, a_s0, a_dp1, a_sp1, a_d1, a_s1;
    if (EXACT) {
        const int i0 = gtid, i1 = gtid + S;
        a_dp0 = dp4[i0]; a_sp0 = sp4[i0]; a_d0 = d4[i0]; a_s0 = s4[i0];
        a_dp1 = dp4[i1]; a_sp1 = sp4[i1]; a_d1 = d4[i1]; a_s1 = s4[i1];
    } else {
        const float4 z4 = make_float4(0.f, 0.f, 0.f, 0.f);
        const int i0 = gtid, i1 = gtid + S;
        const bool p0 = i0 < n4, p1 = i1 < n4;
        a_dp0 = p0 ? dp4[i0] : z4; a_sp0 = p0 ? sp4[i0] : z4;
        a_d0  = p0 ? d4[i0]  : z4; a_s0  = p0 ? s4[i0]  : z4;
        a_dp1 = p1 ? dp4[i1] : z4; a_sp1 = p1 ? sp4[i1] : z4;
        a_d1  = p1 ? d4[i1]  : z4; a_s1  = p1 ? s4[i1]  : z4;
    }

    // Scheduling fence: NO instruction may cross (mask 0). Forces the emitted
    // order: 8x global_load_dwordx4 above, all arithmetic below -> 8 loads in
    // flight per thread. (The "+v" float4 tie from round 9 doesn't compile:
    // tied indirect register inputs unsupported on gfx950.)
    __builtin_amdgcn_sched_barrier(0);

    float a[NACC];
    #pragma unroll
    for (int k = 0; k < NACC; ++k) a[k] = 0.0f;
    process4(a, a_dp0, a_sp0, a_d0, a_s0);
    process4(a, a_dp1, a_sp1, a_d1, a_s1);

    // block reduction via LDS store-then-gather (no shuffles, no atomics)
    #pragma unroll
    for (int k = 0; k < NACC; ++k) red[k][tid] = a[k];     // conflict-free
    __syncthreads();

    if (tid < 192) {
        const int k = tid >> 3;        // 0..23
        const int j = tid & 7;         // 0..7 : owns threads j*32..j*32+31
        const float* row = &red[k][j * 32];
        double s0 = 0.0, s1 = 0.0, s2 = 0.0, s3 = 0.0;
        #pragma unroll
        for (int i = 0; i < 32; i += 4) {
            s0 += (double)row[(i + 0 + tid) & 31];
            s1 += (double)row[(i + 1 + tid) & 31];
            s2 += (double)row[(i + 2 + tid) & 31];
            s3 += (double)row[(i + 3 + tid) & 31];
        }
        red2[k][j] = (s0 + s1) + (s2 + s3);
    }
    __syncthreads();

    if (tid < NACC) {
        double v = 0.0;
        #pragma unroll
        for (int j = 0; j < 8; ++j) v += red2[tid][j];
        // transposed layout: column k contiguous over blocks -> coalesced stage-2
        partial[tid * GRID1 + blockIdx.x] = v;
    }
}

// 1024 threads = 16 waves; wave w reduces cols {w, w+16}. 4 independent
// accumulators so the load batches per column pipeline.
__global__ __launch_bounds__(1024) void amp_final(
    const double* __restrict__ partial, float* __restrict__ out, int n)
{
    __shared__ double tot[NACC];
    const int lane = threadIdx.x & 63;
    const int wave = threadIdx.x >> 6;

    for (int k = wave; k < NACC; k += 16) {
        const double* col = partial + k * GRID1 + lane;
        double v0 = 0.0, v1 = 0.0, v2 = 0.0, v3 = 0.0;
        #pragma unroll
        for (int r = 0; r < GRID1 / 64; r += 4) {
            v0 += col[(r + 0) * 64];
            v1 += col[(r + 1) * 64];
            v2 += col[(r + 2) * 64];
            v3 += col[(r + 3) * 64];
        }
        double v = (v0 + v1) + (v2 + v3);
        #pragma unroll
        for (int off = 32; off > 0; off >>= 1)
            v += __shfl_down(v, off, 64);
        if (lane == 0) tot[k] = v;
    }
    __syncthreads();

    if (threadIdx.x == 0) {
        const double nf = (double)n;
        const double lt = tot[0];
        const double sum_d  = tot[1], sum_d2  = tot[2];
        const double sum_dp = tot[3], sum_dp2 = tot[4];
        const double sum_s  = tot[5], sum_s2  = tot[6];
        const double sum_sp = tot[7], sum_sp2 = tot[8];

        double scale_cost = 1.0 - lt / nf;

        double d_rst = 0.0, s_rst = 0.0, rst_d = 0.0, rst_s = 0.0;
        int cnt = 0;
        #pragma unroll
        for (int i = 0; i < 5; ++i) {
            double c   = tot[9 + 3 * i];
            double sdi = tot[10 + 3 * i];
            double ssi = tot[11 + 3 * i];
            double safe = fmax(c, 1.0);
            double w = sqrt(log(nf / safe));
            double sum_di = w * sdi;
            double sum_si = w * ssi;
            bool has = c > 0.0;
            double nd = (d_rst + sum_di) / safe;
            double ns = (s_rst + sum_si) / safe;
            if (has) {
                d_rst = nd; s_rst = ns;
                rst_d += nd; rst_s += ns;
                cnt++;
            }
        }
        double denom = (cnt == 0) ? 5.0 : (double)cnt;
        rst_d /= denom;
        rst_s /= denom;

        double mean_d  = sum_d / nf,  mean_dp = sum_dp / nf;
        double mean_s  = sum_s / nf,  mean_sp = sum_sp / nf;
        double var_d  = (sum_d2  - nf * mean_d  * mean_d)  / (nf - 1.0);
        double var_dp = (sum_dp2 - nf * mean_dp * mean_dp) / (nf - 1.0);
        double var_s  = (sum_s2  - nf * mean_s  * mean_s)  / (nf - 1.0);
        double var_sp = (sum_sp2 - nf * mean_sp * mean_sp) / (nf - 1.0);

        double dbp_mean_cost = fabs(mean_d - mean_dp) / mean_d;
        double sbp_mean_cost = fabs(mean_s - mean_sp) / mean_s;
        double dbp_var_cost  = fabs(var_d - var_dp) / var_d;
        double sbp_var_cost  = fabs(var_s - var_sp) / var_s;

        out[0] = (float)(rst_d + dbp_mean_cost + dbp_var_cost);
        out[1] = (float)(rst_s + sbp_mean_cost + sbp_var_cost);
        out[2] = (float)scale_cost;
    }
}

extern "C" void kernel_launch(void* const* d_in, const int* in_sizes, int n_in,
                              void* d_out, int out_size, void* d_ws, size_t ws_size,
                              hipStream_t stream) {
    const float* dp = (const float*)d_in[0];   // dbp_pred
    const float* sp = (const float*)d_in[1];   // sbp_pred
    // d_in[2] = mbp_pred (unused), d_in[5] = m (unused)
    const float* d  = (const float*)d_in[3];
    const float* s  = (const float*)d_in[4];
    const int n = in_sizes[0];

    double* partial = (double*)d_ws;           // NACC * GRID1 doubles = 384 KiB
    float* out = (float*)d_out;

    if (n == GRID1 * TPB * 8) {
        hipLaunchKernelGGL((amp_reduce<true>), dim3(GRID1), dim3(TPB), 0, stream,
                           dp, sp, d, s, partial, n);
    } else {
        hipLaunchKernelGGL((amp_reduce<false>), dim3(GRID1), dim3(TPB), 0, stream,
                           dp, sp, d, s, partial, n);
    }
    hipLaunchKernelGGL(amp_final, dim3(1), dim3(1024), 0, stream,
                       partial, out, n);
}

// Round 11
// 25.466 us; speedup vs baseline: 2.3938x; 1.1699x over previous
//
#include <hip/hip_runtime.h>
#include <math.h>

#define NACC 24
#define GRID1 1024
#define TPB 256
#define NTILE 4
// 1024 blocks x 256 threads x 4 tiles x 4 elems = 4194304 exactly

// canonical 24-vector layout:
//  0: lt count (dbp_pred < sbp_pred)
//  1: sum_d   2: sum_d2   3: sum_dp  4: sum_dp2
//  5: sum_s   6: sum_s2   7: sum_sp  8: sum_sp2
//  9+3g: mask-g count   10+3g: mask-g . smape_d   11+3g: mask-g . smape_s

// All-f32 per-thread accumulation (16 elems/thread): sums ~2e-7 rel error,
// counts <= 16 exact in f32; promoted to f64 before cross-thread summation.
__device__ __forceinline__ void process_elem(float* a, float dpv, float spv,
                                             float dv, float sv) {
    a[0] += (dpv < spv) ? 1.0f : 0.0f;
    a[1] += dv;  a[2] = fmaf(dv,  dv,  a[2]);
    a[3] += dpv; a[4] = fmaf(dpv, dpv, a[4]);
    a[5] += sv;  a[6] = fmaf(sv,  sv,  a[6]);
    a[7] += spv; a[8] = fmaf(spv, spv, a[8]);
    float smd = 2.0f * fabsf(dpv - dv) * __builtin_amdgcn_rcpf(fabsf(dpv) + fabsf(dv));
    float sms = 2.0f * fabsf(spv - sv) * __builtin_amdgcn_rcpf(fabsf(spv) + fabsf(sv));
    // mask precedence: & binds tighter than | in the reference
    bool m0 = (sv < 120.0f) && (dv < 80.0f);
    bool m1 = (sv >= 120.0f) && (sv < 130.0f) && (dv < 80.0f);
    bool m2 = ((sv >= 130.0f) && (sv < 140.0f)) || ((dv >= 80.0f) && (dv < 90.0f));
    bool m3 = (sv >= 140.0f) || (dv >= 90.0f);
    bool m4 = (sv > 180.0f) || (dv > 120.0f);
    float w;
    w = m0 ? 1.0f : 0.0f; a[9]  += w; a[10] = fmaf(w, smd, a[10]); a[11] = fmaf(w, sms, a[11]);
    w = m1 ? 1.0f : 0.0f; a[12] += w; a[13] = fmaf(w, smd, a[13]); a[14] = fmaf(w, sms, a[14]);
    w = m2 ? 1.0f : 0.0f; a[15] += w; a[16] = fmaf(w, smd, a[16]); a[17] = fmaf(w, sms, a[17]);
    w = m3 ? 1.0f : 0.0f; a[18] += w; a[19] = fmaf(w, smd, a[19]); a[20] = fmaf(w, sms, a[20]);
    w = m4 ? 1.0f : 0.0f; a[21] += w; a[22] = fmaf(w, smd, a[22]); a[23] = fmaf(w, sms, a[23]);
}

__device__ __forceinline__ void process4(float* a, float4 vdp, float4 vsp,
                                         float4 vd, float4 vs) {
    process_elem(a, vdp.x, vsp.x, vd.x, vs.x);
    process_elem(a, vdp.y, vsp.y, vd.y, vs.y);
    process_elem(a, vdp.z, vsp.z, vd.z, vs.z);
    process_elem(a, vdp.w, vsp.w, vd.w, vs.w);
}

// Software-pipelined persistent-wave grind: 4 tiles/thread, double-buffered
// register staging (named A/B regs, fully static), sched_barrier(0) between
// each issue-group and the previous tile's compute. One block generation
// (1024 blocks = 4/CU), so the HBM latency is paid once per wave, and every
// later tile's latency hides under the previous tile's ~720 compute cycles.
template <bool EXACT>
__global__ __launch_bounds__(TPB, 4) void amp_reduce(
    const float* __restrict__ dp, const float* __restrict__ sp,
    const float* __restrict__ d,  const float* __restrict__ s,
    double* __restrict__ partial, int n)
{
    __shared__ float  red[NACC][TPB];   // 24 KB
    __shared__ double red2[NACC][8];    // 1.5 KB

    const int tid  = threadIdx.x;
    const int n4   = n >> 2;
    const int gtid = blockIdx.x * TPB + tid;
    const int S    = GRID1 * TPB;       // float4 stride between tiles

    const float4* dp4 = (const float4*)dp;
    const float4* sp4 = (const float4*)sp;
    const float4* d4  = (const float4*)d;
    const float4* s4  = (const float4*)s;

    float a[NACC];
    #pragma unroll
    for (int k = 0; k < NACC; ++k) a[k] = 0.0f;

    if (EXACT) {
        int i = gtid;
        // prologue: tiles 0 and 1 in flight
        float4 A0 = dp4[i], A1 = sp4[i], A2 = d4[i], A3 = s4[i];
        i += S;
        float4 B0 = dp4[i], B1 = sp4[i], B2 = d4[i], B3 = s4[i];
        __builtin_amdgcn_sched_barrier(0);
        process4(a, A0, A1, A2, A3);            // tile 0 (covers tile 1)
        i += S;
        A0 = dp4[i]; A1 = sp4[i]; A2 = d4[i]; A3 = s4[i];   // tile 2
        __builtin_amdgcn_sched_barrier(0);
        process4(a, B0, B1, B2, B3);            // tile 1 (covers tile 2)
        i += S;
        B0 = dp4[i]; B1 = sp4[i]; B2 = d4[i]; B3 = s4[i];   // tile 3
        __builtin_amdgcn_sched_barrier(0);
        process4(a, A0, A1, A2, A3);            // tile 2 (covers tile 3)
        process4(a, B0, B1, B2, B3);            // tile 3
    } else {
        const float4 z4 = make_float4(0.f, 0.f, 0.f, 0.f);
        #pragma unroll
        for (int t = 0; t < NTILE; ++t) {
            const int i = gtid + t * S;
            const bool p = i < n4;
            float4 v0 = p ? dp4[i] : z4;
            float4 v1 = p ? sp4[i] : z4;
            float4 v2 = p ? d4[i]  : z4;
            float4 v3 = p ? s4[i]  : z4;
            process4(a, v0, v1, v2, v3);
        }
    }

    // block reduction via LDS store-then-gather (no shuffles, no atomics)
    #pragma unroll
    for (int k = 0; k < NACC; ++k) red[k][tid] = a[k];     // conflict-free
    __syncthreads();

    if (tid < 192) {
        const int k = tid >> 3;        // 0..23
        const int j = tid & 7;         // 0..7 : owns threads j*32..j*32+31
        const float* row = &red[k][j * 32];
        double s0 = 0.0, s1 = 0.0, s2 = 0.0, s3 = 0.0;
        #pragma unroll
        for (int i = 0; i < 32; i += 4) {
            s0 += (double)row[(i + 0 + tid) & 31];
            s1 += (double)row[(i + 1 + tid) & 31];
            s2 += (double)row[(i + 2 + tid) & 31];
            s3 += (double)row[(i + 3 + tid) & 31];
        }
        red2[k][j] = (s0 + s1) + (s2 + s3);
    }
    __syncthreads();

    if (tid < NACC) {
        double v = 0.0;
        #pragma unroll
        for (int j = 0; j < 8; ++j) v += red2[tid][j];
        // transposed layout: column k contiguous over blocks -> coalesced stage-2
        partial[tid * GRID1 + blockIdx.x] = v;
    }
}

// 1024 threads = 16 waves; wave w reduces cols {w, w+16}. 4 independent
// accumulators so the load batches per column pipeline.
__global__ __launch_bounds__(1024) void amp_final(
    const double* __restrict__ partial, float* __restrict__ out, int n)
{
    __shared__ double tot[NACC];
    const int lane = threadIdx.x & 63;
    const int wave = threadIdx.x >> 6;

    for (int k = wave; k < NACC; k += 16) {
        const double* col = partial + k * GRID1 + lane;
        double v0 = 0.0, v1 = 0.0, v2 = 0.0, v3 = 0.0;
        #pragma unroll
        for (int r = 0; r < GRID1 / 64; r += 4) {
            v0 += col[(r + 0) * 64];
            v1 += col[(r + 1) * 64];
            v2 += col[(r + 2) * 64];
            v3 += col[(r + 3) * 64];
        }
        double v = (v0 + v1) + (v2 + v3);
        #pragma unroll
        for (int off = 32; off > 0; off >>= 1)
            v += __shfl_down(v, off, 64);
        if (lane == 0) tot[k] = v;
    }
    __syncthreads();

    if (threadIdx.x == 0) {
        const double nf = (double)n;
        const double lt = tot[0];
        const double sum_d  = tot[1], sum_d2  = tot[2];
        const double sum_dp = tot[3], sum_dp2 = tot[4];
        const double sum_s  = tot[5], sum_s2  = tot[6];
        const double sum_sp = tot[7], sum_sp2 = tot[8];

        double scale_cost = 1.0 - lt / nf;

        double d_rst = 0.0, s_rst = 0.0, rst_d = 0.0, rst_s = 0.0;
        int cnt = 0;
        #pragma unroll
        for (int i = 0; i < 5; ++i) {
            double c   = tot[9 + 3 * i];
            double sdi = tot[10 + 3 * i];
            double ssi = tot[11 + 3 * i];
            double safe = fmax(c, 1.0);
            double w = sqrt(log(nf / safe));
            double sum_di = w * sdi;
            double sum_si = w * ssi;
            bool has = c > 0.0;
            double nd = (d_rst + sum_di) / safe;
            double ns = (s_rst + sum_si) / safe;
            if (has) {
                d_rst = nd; s_rst = ns;
                rst_d += nd; rst_s += ns;
                cnt++;
            }
        }
        double denom = (cnt == 0) ? 5.0 : (double)cnt;
        rst_d /= denom;
        rst_s /= denom;

        double mean_d  = sum_d / nf,  mean_dp = sum_dp / nf;
        double mean_s  = sum_s / nf,  mean_sp = sum_sp / nf;
        double var_d  = (sum_d2  - nf * mean_d  * mean_d)  / (nf - 1.0);
        double var_dp = (sum_dp2 - nf * mean_dp * mean_dp) / (nf - 1.0);
        double var_s  = (sum_s2  - nf * mean_s  * mean_s)  / (nf - 1.0);
        double var_sp = (sum_sp2 - nf * mean_sp * mean_sp) / (nf - 1.0);

        double dbp_mean_cost = fabs(mean_d - mean_dp) / mean_d;
        double sbp_mean_cost = fabs(mean_s - mean_sp) / mean_s;
        double dbp_var_cost  = fabs(var_d - var_dp) / var_d;
        double sbp_var_cost  = fabs(var_s - var_sp) / var_s;

        out[0] = (float)(rst_d + dbp_mean_cost + dbp_var_cost);
        out[1] = (float)(rst_s + sbp_mean_cost + sbp_var_cost);
        out[2] = (float)scale_cost;
    }
}

extern "C" void kernel_launch(void* const* d_in, const int* in_sizes, int n_in,
                              void* d_out, int out_size, void* d_ws, size_t ws_size,
                              hipStream_t stream) {
    const float* dp = (const float*)d_in[0];   // dbp_pred
    const float* sp = (const float*)d_in[1];   // sbp_pred
    // d_in[2] = mbp_pred (unused), d_in[5] = m (unused)
    const float* d  = (const float*)d_in[3];
    const float* s  = (const float*)d_in[4];
    const int n = in_sizes[0];

    double* partial = (double*)d_ws;           // NACC * GRID1 doubles = 192 KiB
    float* out = (float*)d_out;

    if (n == GRID1 * TPB * 4 * NTILE) {
        hipLaunchKernelGGL((amp_reduce<true>), dim3(GRID1), dim3(TPB), 0, stream,
                           dp, sp, d, s, partial, n);
    } else {
        hipLaunchKernelGGL((amp_reduce<false>), dim3(GRID1), dim3(TPB), 0, stream,
                           dp, sp, d, s, partial, n);
    }
    hipLaunchKernelGGL(amp_final, dim3(1), dim3(1024), 0, stream,
                       partial, out, n);
}